// Round 11
// baseline (174.749 us; speedup 1.0000x reference)
//
#include <hip/hip_runtime.h>
#include <hip/hip_bf16.h>
#include <stdint.h>

typedef unsigned short ushort_t;
typedef unsigned long long u64;
typedef __attribute__((ext_vector_type(8))) short short8;   // 8 bf16 (4 VGPRs)
typedef __attribute__((ext_vector_type(4))) float f32x4;

#define N_NODES 384
#define HF      512
#define IT      12        // i-rows per attention unit: 32 tiles x 8 heads = 256
#define NBLK    256

__device__ inline ushort_t f2bf(float f) {
  __hip_bfloat16 b = __float2bfloat16(f);
  return *reinterpret_cast<ushort_t*>(&b);
}
__device__ inline float bf2f_u(ushort_t u) {
  union { float f; uint32_t i; } v; v.i = ((uint32_t)u) << 16; return v.f;
}
__device__ inline short8 pack8(const float* s) {
  short8 r;
#pragma unroll
  for (int j = 0; j < 8; ++j) r[j] = (short)f2bf(s[j]);
  return r;
}

// Zero the spin-barrier counters (ws is re-poisoned 0xAA before every call).
__global__ void init_bar(unsigned* bar) {
  if (threadIdx.x < 4) bar[threadIdx.x] = 0;
}

// Corrected device-scope grid barrier (R6 defect: __threadfence() by ALL
// threads = ~98k L2 flushes/barrier). Protocol: __syncthreads drains each
// wave's stores to L2 (L1 write-through, compiler emits vmcnt(0) before
// s_barrier); ONE thread per block does acq_rel agent-scope fetch_add
// (single buffer_wbl2) and acquire-spins (invalidate on load); trailing
// __syncthreads releases the block. 256 flushes/barrier total.
__device__ __forceinline__ void gridbar(unsigned* cnt) {
  __syncthreads();
  if (threadIdx.x == 0) {
    __hip_atomic_fetch_add(cnt, 1u, __ATOMIC_ACQ_REL, __HIP_MEMORY_SCOPE_AGENT);
    while (__hip_atomic_load(cnt, __ATOMIC_ACQUIRE,
                             __HIP_MEMORY_SCOPE_AGENT) < NBLK) {
      __builtin_amdgcn_s_sleep(1);
    }
  }
  __syncthreads();
}

// ---------------------------------------------------------------------------
// GEMM phase (R8-verified 16m x 16n wave tile; all 6 waves work).
// unit u = b*6 + wave in [0,1536): m0 = (u>>6)*16, n0 = (u&63)*16.
// G[m][n] = sum_k X[m][k]*W[k][n]; in-register fp32->bf16 cvt.
//  n <  512 (gl): glb bf16 [m][n]
//  n >= 512 (gr): G fp32 [m][512+n'] and grT bf16 [n'][m] (k-contig)
// Layer 0 extra: adjacency bitmasks (blocks 0..95, waves 0..3, 1 row each).
// ---------------------------------------------------------------------------
__device__ __forceinline__ void gemm_phase(
    const float* X, const float* WL, const float* WR,
    float* G, ushort_t* glb, ushort_t* grT,
    const int* adj, u64* mbits)
{
  const int t = threadIdx.x, wave = t >> 6, lane = t & 63;
  const int lm = lane & 15, q = lane >> 4;
  const int u = blockIdx.x * 6 + wave;
  const int m0 = (u >> 6) * 16;
  const int n0 = (u & 63) * 16;
  const float* Wp = (n0 < 512) ? (WL + n0) : (WR + (n0 - 512));
  const float* Arow = X + (m0 + lm) * HF;

  f32x4 acc = {0.f, 0.f, 0.f, 0.f};
#pragma unroll 4
  for (int kc = 0; kc < 16; ++kc) {
    const int kbase = kc * 32 + q * 8;
    float4 a0 = *(const float4*)(Arow + kbase);
    float4 a1 = *(const float4*)(Arow + kbase + 4);
    float av8[8] = {a0.x, a0.y, a0.z, a0.w, a1.x, a1.y, a1.z, a1.w};
    short8 af = pack8(av8);
    float bf8[8];
#pragma unroll
    for (int j = 0; j < 8; ++j) bf8[j] = Wp[(kbase + j) * HF + lm];
    short8 b = pack8(bf8);
    acc = __builtin_amdgcn_mfma_f32_16x16x32_bf16(af, b, acc, 0, 0, 0);
  }
  if (n0 < 512) {
#pragma unroll
    for (int r = 0; r < 4; ++r)
      glb[(m0 + q * 4 + r) * HF + n0 + lm] = f2bf(acc[r]);
  } else {
#pragma unroll
    for (int r = 0; r < 4; ++r)
      G[(m0 + q * 4 + r) * 1024 + n0 + lm] = acc[r];
    int c0 = n0 - 512;
    uint2 p0;
    p0.x = (uint32_t)f2bf(acc[0]) | ((uint32_t)f2bf(acc[1]) << 16);
    p0.y = (uint32_t)f2bf(acc[2]) | ((uint32_t)f2bf(acc[3]) << 16);
    *(uint2*)&grT[(c0 + lm) * 384 + m0 + q * 4] = p0;
  }
  // layer-0 only: adjacency bitmasks (self-loop OR'd in)
  if (adj != nullptr && blockIdx.x < 96 && wave < 4) {
    int row = blockIdx.x * 4 + wave;
#pragma unroll
    for (int w = 0; w < 6; ++w) {
      int j = w * 64 + lane;
      u64 m = __ballot(adj[row * N_NODES + j] != 0 || row == j);
      if (lane == 0) mbits[row * 6 + w] = m;
    }
  }
}

// ---------------------------------------------------------------------------
// Attention phase (R10's verified body). Unit = blockIdx: i-tile = b>>3,
// head = b&7. Async global->LDS DMA staging with XOR swizzle; phase 1 pure
// VALU; phase 2 softmax; phase 3 MFMA P @ grT; fused epilogue.
// layer 0: ELU + x residual -> xcur fp32. layer 1: + xcur -> fout fp32.
// ---------------------------------------------------------------------------
__device__ __forceinline__ void attn_phase(int layer,
    const float* G, const ushort_t* glb, const ushort_t* grT,
    const u64* mbits, const float* resid_in, const float* avec,
    float* xcur_out, float* f_out,
    char* smem, float* s_bri, u64 (*s_mask)[6])
{
  ushort_t (*s_gl)[64]     = (ushort_t(*)[64])smem;            // 49152 B
  float    (*s_e)[N_NODES] = (float(*)[N_NODES])smem;          // 12x384 fp32
  ushort_t (*s_pb)[392]    = (ushort_t(*)[392])(smem + 18432); // 16x392 bf16

  const int t = threadIdx.x;
  const int i0 = (blockIdx.x >> 3) * IT, h = blockIdx.x & 7;
  const int lane = t & 63, wave = t >> 6;

  // -- issue async global->LDS DMA first (8 x 16 B per thread) --
#pragma unroll
  for (int rep = 0; rep < 8; ++rep) {
    int idx = rep * 384 + t, row = idx >> 3, cl = idx & 7;
    int cg = cl ^ (row & 7);
    const ushort_t* gsrc = glb + row * HF + h * 64 + cg * 8;
    __builtin_amdgcn_global_load_lds(
        (const __attribute__((address_space(1))) uint32_t*)gsrc,
        (__attribute__((address_space(3))) uint32_t*)(smem + idx * 16),
        16, 0, 0);
  }

  // -- overlapped: masks (72 u64) + bri dot --
  if (t < 72) ((u64*)s_mask)[t] = mbits[i0 * 6 + t];
  if (t >= 128 && t < 320) {
    int u = t - 128, il = u >> 4, fg = u & 15;
    float4 g4 = *(const float4*)(G + (i0 + il) * 1024 + 512 + h * 64 + fg * 4);
    float4 a4 = *(const float4*)(avec + fg * 4);
    float s = a4.x * g4.x + a4.y * g4.y + a4.z * g4.z + a4.w * g4.w;
    s += __shfl_xor(s, 1); s += __shfl_xor(s, 2);
    s += __shfl_xor(s, 4); s += __shfl_xor(s, 8);
    if (fg == 0) s_bri[il] = s;
  }
  __syncthreads();   // drains DMA + overlapped work

  // -- own j-row -> 64 VGPRs (chunk cg at slot cg^(t&7)); avec -> VGPRs --
  float gl[64], av[64];
  {
    const int sw = t & 7;
#pragma unroll
    for (int cg = 0; cg < 8; ++cg) {
      short8 v = *(const short8*)&s_gl[t][(cg ^ sw) * 8];
#pragma unroll
      for (int u2 = 0; u2 < 8; ++u2)
        gl[cg * 8 + u2] = bf2f_u((ushort_t)v[u2]);
    }
#pragma unroll
    for (int c = 0; c < 16; ++c) {
      float4 a4 = ((const float4*)avec)[c];
      av[c * 4] = a4.x; av[c * 4 + 1] = a4.y;
      av[c * 4 + 2] = a4.z; av[c * 4 + 3] = a4.w;
    }
  }
  float accl = 0.f;
#pragma unroll
  for (int f = 0; f < 64; ++f) accl += av[f] * gl[f];
  __syncthreads();   // s_gl dead; region becomes s_e / s_pb

  // -- phase 1: scores straight to LDS --
  const int jw = t >> 6, jb = t & 63;
#pragma unroll
  for (int il = 0; il < IT; ++il) {
    const float4* gr4 = (const float4*)(G + (i0 + il) * 1024 + 512 + h * 64);
    float acc = 0.f;
#pragma unroll
    for (int c = 0; c < 16; ++c) {
      float4 g4 = gr4[c];
      acc += av[c * 4]     * fabsf(gl[c * 4]     + g4.x);
      acc += av[c * 4 + 1] * fabsf(gl[c * 4 + 1] + g4.y);
      acc += av[c * 4 + 2] * fabsf(gl[c * 4 + 2] + g4.z);
      acc += av[c * 4 + 3] * fabsf(gl[c * 4 + 3] + g4.w);
    }
    bool m = (s_mask[il][jw] >> jb) & 1;
    float e = 0.6f * (accl + s_bri[il]) + 0.4f * acc;
    s_e[il][t] = m ? e : -1e30f;
  }
#pragma unroll
  for (int r4 = 0; r4 < 4; ++r4) s_pb[IT + r4][t] = 0;  // zero P rows 12..15
  __syncthreads();

  // -- phase 2: softmax over j per row; write normalized P bf16 --
#pragma unroll
  for (int rep = 0; rep < 2; ++rep) {
    int il = wave * 2 + rep;
    float v[6];
    float mx = -1e30f;
#pragma unroll
    for (int c = 0; c < 6; ++c) { v[c] = s_e[il][lane + 64 * c]; mx = fmaxf(mx, v[c]); }
#pragma unroll
    for (int off = 32; off; off >>= 1) mx = fmaxf(mx, __shfl_xor(mx, off));
    float sum = 0.f;
#pragma unroll
    for (int c = 0; c < 6; ++c) { v[c] = __expf(v[c] - mx); sum += v[c]; }
#pragma unroll
    for (int off = 32; off; off >>= 1) sum += __shfl_xor(sum, off);
    float inv = 1.0f / sum;
#pragma unroll
    for (int c = 0; c < 6; ++c) s_pb[il][lane + 64 * c] = f2bf(v[c] * inv);
  }
  __syncthreads();

  // -- phase 3: MFMA aggregation out[12 i][64 f] = P[12][384] @ gr[384][64] --
  if (wave < 4) {
    const int lm = lane & 15, q = lane >> 4;
    const int f0 = wave * 16;
    const ushort_t* Brow = grT + (h * 64 + f0 + lm) * 384;
    f32x4 acc = {0.f, 0.f, 0.f, 0.f};
#pragma unroll
    for (int kc = 0; kc < 12; ++kc) {
      short8 af = *(const short8*)&s_pb[lm][kc * 32 + q * 8];
      short8 bf = *(const short8*)&Brow[kc * 32 + q * 8];
      acc = __builtin_amdgcn_mfma_f32_16x16x32_bf16(af, bf, acc, 0, 0, 0);
    }
    if (q < 3) {                                    // D rows 0..11
#pragma unroll
      for (int r = 0; r < 4; ++r) {
        int i = i0 + q * 4 + r;
        int off = i * HF + h * 64 + f0 + lm;
        float o = acc[r];
        if (layer == 0) {
          float oe = (o > 0.f) ? o : (__expf(o) - 1.f);   // ELU
          xcur_out[off] = resid_in[off] + oe;   // fp32 residual for layer 1
        } else {
          f_out[off] = resid_in[off] + o;       // final output, fp32
        }
      }
    }
  }
}

// ---------------------------------------------------------------------------
// Mega kernel v2: gemm0 | attn0 | gemm1 | attn1 with 3 corrected grid
// barriers. grid 256 x 384 threads, ~50 KB LDS -> 1 block/CU, co-resident.
// ---------------------------------------------------------------------------
__global__ __launch_bounds__(384) void mega(
    const float* __restrict__ x, const int* __restrict__ adj,
    const float* __restrict__ Wl0, const float* __restrict__ Wr0,
    const float* __restrict__ a0,  const float* __restrict__ Wl1,
    const float* __restrict__ Wr1, const float* __restrict__ a1,
    float* out, float* G, ushort_t* glb, ushort_t* grT,
    u64* mbits, float* xcur, unsigned* bar)
{
  __shared__ __align__(16) char smem[49152];
  __shared__ float s_bri[IT];
  __shared__ u64   s_mask[IT][6];

  gemm_phase(x, Wl0, Wr0, G, glb, grT, adj, mbits);
  gridbar(bar + 0);

  attn_phase(0, G, glb, grT, mbits, x, a0, xcur, out, smem, s_bri, s_mask);
  gridbar(bar + 1);

  gemm_phase(xcur, Wl1, Wr1, G, glb, grT, nullptr, nullptr);
  gridbar(bar + 2);

  attn_phase(1, G, glb, grT, mbits, xcur, a1, xcur, out, smem, s_bri, s_mask);
}

// ---------------------------------------------------------------------------
extern "C" void kernel_launch(void* const* d_in, const int* in_sizes, int n_in,
                              void* d_out, int out_size, void* d_ws, size_t ws_size,
                              hipStream_t stream) {
  const float* x   = (const float*)d_in[0];
  const int*   adj = (const int*)d_in[1];
  const float* Wl0 = (const float*)d_in[2];
  const float* Wr0 = (const float*)d_in[3];
  const float* a0  = (const float*)d_in[4];
  const float* Wl1 = (const float*)d_in[5];
  const float* Wr1 = (const float*)d_in[6];
  const float* a1  = (const float*)d_in[7];
  float* out = (float*)d_out;

  char* ws = (char*)d_ws;
  float*    G    = (float*)   (ws + 0L);            // 1.5 MB (gr half used)
  ushort_t* grT  = (ushort_t*)(ws + (2L << 20));    // 384 KB gr^T bf16
  ushort_t* glb  = (ushort_t*)(ws + (3L << 20));    // 384 KB gl bf16
  u64*      mbits= (u64*)     (ws + (4L << 20));    // 18 KB adjacency bits
  float*    xcur = (float*)   (ws + (5L << 20));    // 768 KB fp32 residual
  unsigned* bar  = (unsigned*)(ws + (6L << 20));    // 4 barrier counters

  init_bar<<<1, 64, 0, stream>>>(bar);
  mega<<<NBLK, 384, 0, stream>>>(x, adj, Wl0, Wr0, a0, Wl1, Wr1, a1, out,
                                 G, glb, grT, mbits, xcur, bar);
}

// Round 12
// 124.946 us; speedup vs baseline: 1.3986x; 1.3986x over previous
//
#include <hip/hip_runtime.h>
#include <hip/hip_bf16.h>
#include <stdint.h>

typedef unsigned short ushort_t;
typedef unsigned long long u64;
typedef __attribute__((ext_vector_type(8))) short short8;   // 8 bf16 (4 VGPRs)
typedef __attribute__((ext_vector_type(4))) float f32x4;

#define N_NODES 384
#define HF      512
#define IT      12        // i-rows per attention block: 32 tiles x 8 heads = 256

__device__ inline ushort_t f2bf(float f) {
  __hip_bfloat16 b = __float2bfloat16(f);
  return *reinterpret_cast<ushort_t*>(&b);
}
__device__ inline float bf2f_u(ushort_t u) {
  union { float f; uint32_t i; } v; v.i = ((uint32_t)u) << 16; return v.f;
}
__device__ inline short8 pack8(const float* s) {
  short8 r;
#pragma unroll
  for (int j = 0; j < 8; ++j) r[j] = (short)f2bf(s[j]);
  return r;
}

// ---------------------------------------------------------------------------
// Kernel 1/3: dual GEMM, raw fp32 inputs, in-register bf16 cvt.
// G[m][n] = sum_k X[m][k]*W[k][n], n in [0,1024), W = [WL | WR] fp32.
//  n <  512 (gl): glb bf16 [m][n]
//  n >= 512 (gr): G fp32 [m][512+n'] and grT bf16 [n'][m] (k-contig)
// grid (24,16), 256 thr = 4 waves; wave computes 16m x 16n (1536 waves =
// 6/CU device-wide, all 256 CUs busy -> TLP hides strided-B L2 latency).
// [R8-validated shape; R10 ran (24,8)/32n leaving 64 CUs idle.]
// Layer 0 extra: adjacency bitmasks (by==0 blocks).
// ---------------------------------------------------------------------------
__global__ __launch_bounds__(256) void gemm_direct(
    const float* __restrict__ X, const float* __restrict__ WL,
    const float* __restrict__ WR, float* __restrict__ G,
    ushort_t* __restrict__ glb, ushort_t* __restrict__ grT,
    const int* __restrict__ adj, u64* __restrict__ mbits)
{
  const int t = threadIdx.x, wave = t >> 6, lane = t & 63;
  const int lm = lane & 15, q = lane >> 4;
  const int m0 = blockIdx.x * 16;
  const int n0 = (blockIdx.y * 4 + wave) * 16;
  const float* Wp = (n0 < 512) ? (WL + n0) : (WR + (n0 - 512));
  const float* Arow = X + (m0 + lm) * HF;

  f32x4 acc = {0.f, 0.f, 0.f, 0.f};
#pragma unroll 4
  for (int kc = 0; kc < 16; ++kc) {
    const int kbase = kc * 32 + q * 8;
    float4 a0 = *(const float4*)(Arow + kbase);
    float4 a1 = *(const float4*)(Arow + kbase + 4);
    float av8[8] = {a0.x, a0.y, a0.z, a0.w, a1.x, a1.y, a1.z, a1.w};
    short8 af = pack8(av8);
    float bf8[8];
#pragma unroll
    for (int j = 0; j < 8; ++j) bf8[j] = Wp[(kbase + j) * HF + lm];
    short8 b = pack8(bf8);
    acc = __builtin_amdgcn_mfma_f32_16x16x32_bf16(af, b, acc, 0, 0, 0);
  }
  if (n0 < 512) {
#pragma unroll
    for (int r = 0; r < 4; ++r)
      glb[(m0 + q * 4 + r) * HF + n0 + lm] = f2bf(acc[r]);
  } else {
#pragma unroll
    for (int r = 0; r < 4; ++r)
      G[(m0 + q * 4 + r) * 1024 + n0 + lm] = acc[r];
    int c0 = n0 - 512;
    uint2 p0;
    p0.x = (uint32_t)f2bf(acc[0]) | ((uint32_t)f2bf(acc[1]) << 16);
    p0.y = (uint32_t)f2bf(acc[2]) | ((uint32_t)f2bf(acc[3]) << 16);
    *(uint2*)&grT[(c0 + lm) * 384 + m0 + q * 4] = p0;
  }
  // layer-0 only: adjacency bitmasks (self-loop OR'd in), by==0 blocks
  if (adj != nullptr && blockIdx.y == 0) {
    int rbase = (blockIdx.x * 4 + wave) * 4;
    for (int rr = 0; rr < 4; ++rr) {
      int row = rbase + rr;
#pragma unroll
      for (int w = 0; w < 6; ++w) {
        int j = w * 64 + lane;
        u64 m = __ballot(adj[row * N_NODES + j] != 0 || row == j);
        if (lane == 0) mbits[row * 6 + w] = m;
      }
    }
  }
}

// ---------------------------------------------------------------------------
// Kernel 2/4: fused GATv2 attention (byte-identical to R10).
// Block = (12-row i-tile, head), 384 thr, grid (32,8) = 256 blocks = 1/CU.
// Staging: __builtin_amdgcn_global_load_lds width=16, XOR-swizzled chunks;
// DMA issued first, overlapped with mask/bri work, drained at the barrier.
// Phase 1: gl_j + avec in VGPRs, gr via wave-uniform float4 loads, scores
// straight to LDS. Phase 2 softmax -> P bf16. Phase 3 MFMA P @ grT.
// LAYER 0: ELU + x residual -> xcur fp32. LAYER 1: + xcur -> out fp32.
// ---------------------------------------------------------------------------
template <int LAYER>
__global__ __launch_bounds__(384) void attn_fused(
    const float* __restrict__ G, const ushort_t* __restrict__ glb,
    const ushort_t* __restrict__ grT, const u64* __restrict__ mbits,
    const float* __restrict__ resid_in, const float* __restrict__ avec,
    float* __restrict__ xcur_out, float* __restrict__ f_out)
{
  // s_gl [384][64] bf16 (unpadded, swizzled) = 49152 B, barrier-aliased with
  // { s_e fp32 12x384 (18432) + s_pb bf16 16x392 (12544) = 30976 }.
  __shared__ __align__(16) char smem[49152];
  ushort_t (*s_gl)[64]     = (ushort_t(*)[64])smem;
  float    (*s_e)[N_NODES] = (float(*)[N_NODES])smem;
  ushort_t (*s_pb)[392]    = (ushort_t(*)[392])(smem + 18432);
  __shared__ float s_bri[IT];
  __shared__ u64   s_mask[IT][6];

  const int t = threadIdx.x;
  const int i0 = blockIdx.x * IT, h = blockIdx.y;
  const int lane = t & 63, wave = t >> 6;

  // -- phase 0b first: issue async global->LDS DMA (8 x 16 B per thread) --
#pragma unroll
  for (int rep = 0; rep < 8; ++rep) {
    int idx = rep * 384 + t, row = idx >> 3, cl = idx & 7;
    int cg = cl ^ (row & 7);
    const ushort_t* gsrc = glb + row * HF + h * 64 + cg * 8;
    __builtin_amdgcn_global_load_lds(
        (const __attribute__((address_space(1))) uint32_t*)gsrc,
        (__attribute__((address_space(3))) uint32_t*)(smem + idx * 16),
        16, 0, 0);
  }

  // -- phase 0a (overlapped with DMA): masks (72 u64) + bri dot --
  if (t < 72) ((u64*)s_mask)[t] = mbits[i0 * 6 + t];
  if (t >= 128 && t < 320) {
    int u = t - 128, il = u >> 4, fg = u & 15;
    float4 g4 = *(const float4*)(G + (i0 + il) * 1024 + 512 + h * 64 + fg * 4);
    float4 a4 = *(const float4*)(avec + fg * 4);
    float s = a4.x * g4.x + a4.y * g4.y + a4.z * g4.z + a4.w * g4.w;
    s += __shfl_xor(s, 1); s += __shfl_xor(s, 2);
    s += __shfl_xor(s, 4); s += __shfl_xor(s, 8);
    if (fg == 0) s_bri[il] = s;
  }
  __syncthreads();   // drains DMA (vmcnt) + phase 0a

  // -- own j-row -> 64 VGPRs (read chunk cg at slot cg^(t&7)); avec -> VGPRs --
  float gl[64], av[64];
  {
    const int sw = t & 7;
#pragma unroll
    for (int cg = 0; cg < 8; ++cg) {
      short8 v = *(const short8*)&s_gl[t][(cg ^ sw) * 8];
#pragma unroll
      for (int u2 = 0; u2 < 8; ++u2)
        gl[cg * 8 + u2] = bf2f_u((ushort_t)v[u2]);
    }
#pragma unroll
    for (int c = 0; c < 16; ++c) {
      float4 a4 = ((const float4*)avec)[c];
      av[c * 4] = a4.x; av[c * 4 + 1] = a4.y;
      av[c * 4 + 2] = a4.z; av[c * 4 + 3] = a4.w;
    }
  }
  float accl = 0.f;
#pragma unroll
  for (int f = 0; f < 64; ++f) accl += av[f] * gl[f];
  __syncthreads();   // s_gl dead; region becomes s_e / s_pb

  // -- phase 1: scores, written straight to LDS (no private arrays) --
  const int jw = t >> 6, jb = t & 63;
#pragma unroll
  for (int il = 0; il < IT; ++il) {
    const float4* gr4 = (const float4*)(G + (i0 + il) * 1024 + 512 + h * 64);
    float acc = 0.f;
#pragma unroll
    for (int c = 0; c < 16; ++c) {
      float4 g4 = gr4[c];
      acc += av[c * 4]     * fabsf(gl[c * 4]     + g4.x);
      acc += av[c * 4 + 1] * fabsf(gl[c * 4 + 1] + g4.y);
      acc += av[c * 4 + 2] * fabsf(gl[c * 4 + 2] + g4.z);
      acc += av[c * 4 + 3] * fabsf(gl[c * 4 + 3] + g4.w);
    }
    bool m = (s_mask[il][jw] >> jb) & 1;
    float e = 0.6f * (accl + s_bri[il]) + 0.4f * acc;
    s_e[il][t] = m ? e : -1e30f;
  }
#pragma unroll
  for (int r4 = 0; r4 < 4; ++r4) s_pb[IT + r4][t] = 0;  // zero P rows 12..15
  __syncthreads();

  // -- phase 2: softmax over j per row; write normalized P bf16 --
#pragma unroll
  for (int rep = 0; rep < 2; ++rep) {
    int il = wave * 2 + rep;
    float v[6];
    float mx = -1e30f;
#pragma unroll
    for (int c = 0; c < 6; ++c) { v[c] = s_e[il][lane + 64 * c]; mx = fmaxf(mx, v[c]); }
#pragma unroll
    for (int off = 32; off; off >>= 1) mx = fmaxf(mx, __shfl_xor(mx, off));
    float sum = 0.f;
#pragma unroll
    for (int c = 0; c < 6; ++c) { v[c] = __expf(v[c] - mx); sum += v[c]; }
#pragma unroll
    for (int off = 32; off; off >>= 1) sum += __shfl_xor(sum, off);
    float inv = 1.0f / sum;
#pragma unroll
    for (int c = 0; c < 6; ++c) s_pb[il][lane + 64 * c] = f2bf(v[c] * inv);
  }
  __syncthreads();

  // -- phase 3: MFMA aggregation out[12 i][64 f] = P[12][384] @ gr[384][64] --
  if (wave < 4) {
    const int lm = lane & 15, q = lane >> 4;
    const int f0 = wave * 16;
    const ushort_t* Brow = grT + (h * 64 + f0 + lm) * 384;
    f32x4 acc = {0.f, 0.f, 0.f, 0.f};
#pragma unroll
    for (int kc = 0; kc < 12; ++kc) {
      short8 af = *(const short8*)&s_pb[lm][kc * 32 + q * 8];
      short8 bf = *(const short8*)&Brow[kc * 32 + q * 8];
      acc = __builtin_amdgcn_mfma_f32_16x16x32_bf16(af, bf, acc, 0, 0, 0);
    }
    if (q < 3) {                                    // D rows 0..11
#pragma unroll
      for (int r = 0; r < 4; ++r) {
        int i = i0 + q * 4 + r;
        int off = i * HF + h * 64 + f0 + lm;
        float o = acc[r];
        if (LAYER == 0) {
          float oe = (o > 0.f) ? o : (__expf(o) - 1.f);   // ELU
          xcur_out[off] = resid_in[off] + oe;   // fp32 residual for layer 1
        } else {
          f_out[off] = resid_in[off] + o;       // final output, fp32
        }
      }
    }
  }
}

// ---------------------------------------------------------------------------
extern "C" void kernel_launch(void* const* d_in, const int* in_sizes, int n_in,
                              void* d_out, int out_size, void* d_ws, size_t ws_size,
                              hipStream_t stream) {
  const float* x   = (const float*)d_in[0];
  const int*   adj = (const int*)d_in[1];
  const float* Wl0 = (const float*)d_in[2];
  const float* Wr0 = (const float*)d_in[3];
  const float* a0  = (const float*)d_in[4];
  const float* Wl1 = (const float*)d_in[5];
  const float* Wr1 = (const float*)d_in[6];
  const float* a1  = (const float*)d_in[7];
  float* out = (float*)d_out;

  char* ws = (char*)d_ws;
  float*    G    = (float*)   (ws + 0L);            // 1.5 MB (gr half used)
  ushort_t* grT  = (ushort_t*)(ws + (2L << 20));    // 384 KB gr^T bf16
  ushort_t* glb  = (ushort_t*)(ws + (3L << 20));    // 384 KB gl bf16
  u64*      mbits= (u64*)     (ws + (4L << 20));    // 18 KB adjacency bits
  float*    xcur = (float*)   (ws + (5L << 20));    // 768 KB fp32 residual

  gemm_direct<<<dim3(24, 16), 256, 0, stream>>>(x, Wl0, Wr0, G, glb, grT,
                                                adj, mbits);
  attn_fused<0><<<dim3(32, 8), 384, 0, stream>>>(G, glb, grT, mbits, x, a0,
                                                 xcur, nullptr);
  gemm_direct<<<dim3(24, 16), 256, 0, stream>>>(xcur, Wl1, Wr1, G, glb, grT,
                                                nullptr, nullptr);
  attn_fused<1><<<dim3(32, 8), 384, 0, stream>>>(G, glb, grT, mbits, xcur, a1,
                                                 nullptr, out);
}

// Round 13
// 118.670 us; speedup vs baseline: 1.4726x; 1.0529x over previous
//
#include <hip/hip_runtime.h>
#include <hip/hip_bf16.h>
#include <stdint.h>

typedef unsigned short ushort_t;
typedef unsigned long long u64;
typedef __attribute__((ext_vector_type(8))) short short8;   // 8 bf16 (4 VGPRs)
typedef __attribute__((ext_vector_type(4))) float f32x4;

#define N_NODES 384
#define HF      512
#define IT      12        // i-rows per attention block: 32 tiles x 8 heads = 256

__device__ inline ushort_t f2bf(float f) {
  __hip_bfloat16 b = __float2bfloat16(f);
  return *reinterpret_cast<ushort_t*>(&b);
}
__device__ inline float bf2f_u(ushort_t u) {
  union { float f; uint32_t i; } v; v.i = ((uint32_t)u) << 16; return v.f;
}
__device__ inline short8 pack8(const float* s) {
  short8 r;
#pragma unroll
  for (int j = 0; j < 8; ++j) r[j] = (short)f2bf(s[j]);
  return r;
}

// ---------------------------------------------------------------------------
// Kernel 1/3: dual GEMM, raw fp32 inputs, in-register bf16 cvt (R10 shape —
// (24,8)/32n-per-wave; R8+R12 both showed the 16n/384-block variant is ~+3
// µs/launch worse: per-block fixed cost beats TLP at this size).
// G[m][n] = sum_k X[m][k]*W[k][n], n in [0,1024), W = [WL | WR] fp32.
//  n <  512 (gl): glb bf16 [m][n]
//  n >= 512 (gr): G fp32 [m][512+n'] and grT bf16 [n'][m] (k-contig)
// grid (24, 8), 256 threads = 4 waves; wave computes 16m x 32n.
// Layer 0 extra: adjacency bitmasks (by==0 blocks).
// ---------------------------------------------------------------------------
__global__ __launch_bounds__(256) void gemm_direct(
    const float* __restrict__ X, const float* __restrict__ WL,
    const float* __restrict__ WR, float* __restrict__ G,
    ushort_t* __restrict__ glb, ushort_t* __restrict__ grT,
    const int* __restrict__ adj, u64* __restrict__ mbits)
{
  const int t = threadIdx.x, wave = t >> 6, lane = t & 63;
  const int lm = lane & 15, q = lane >> 4;
  const int m0 = blockIdx.x * 16;
  const int n0 = (blockIdx.y * 4 + wave) * 32;
  const float* Wp = (n0 < 512) ? (WL + n0) : (WR + (n0 - 512));
  const float* Arow = X + (m0 + lm) * HF;

  f32x4 acc0 = {0.f, 0.f, 0.f, 0.f};
  f32x4 acc1 = {0.f, 0.f, 0.f, 0.f};
#pragma unroll 4
  for (int kc = 0; kc < 16; ++kc) {
    const int kbase = kc * 32 + q * 8;
    float4 a0 = *(const float4*)(Arow + kbase);
    float4 a1 = *(const float4*)(Arow + kbase + 4);
    float av8[8] = {a0.x, a0.y, a0.z, a0.w, a1.x, a1.y, a1.z, a1.w};
    short8 af = pack8(av8);
    float b0f[8], b1f[8];
#pragma unroll
    for (int j = 0; j < 8; ++j) {
      const float* r = Wp + (kbase + j) * HF;   // 64 lanes -> ~4 lines/instr
      b0f[j] = r[lm];
      b1f[j] = r[16 + lm];
    }
    short8 b0 = pack8(b0f);
    short8 b1 = pack8(b1f);
    acc0 = __builtin_amdgcn_mfma_f32_16x16x32_bf16(af, b0, acc0, 0, 0, 0);
    acc1 = __builtin_amdgcn_mfma_f32_16x16x32_bf16(af, b1, acc1, 0, 0, 0);
  }
  if (n0 < 512) {
#pragma unroll
    for (int r = 0; r < 4; ++r) {
      int m = m0 + q * 4 + r;
      glb[m * HF + n0 + lm]      = f2bf(acc0[r]);
      glb[m * HF + n0 + 16 + lm] = f2bf(acc1[r]);
    }
  } else {
#pragma unroll
    for (int r = 0; r < 4; ++r) {
      int m = m0 + q * 4 + r;
      G[m * 1024 + n0 + lm]      = acc0[r];
      G[m * 1024 + n0 + 16 + lm] = acc1[r];
    }
    int c0 = n0 - 512;
    uint2 p0, p1;
    p0.x = (uint32_t)f2bf(acc0[0]) | ((uint32_t)f2bf(acc0[1]) << 16);
    p0.y = (uint32_t)f2bf(acc0[2]) | ((uint32_t)f2bf(acc0[3]) << 16);
    p1.x = (uint32_t)f2bf(acc1[0]) | ((uint32_t)f2bf(acc1[1]) << 16);
    p1.y = (uint32_t)f2bf(acc1[2]) | ((uint32_t)f2bf(acc1[3]) << 16);
    *(uint2*)&grT[(c0 + lm) * 384 + m0 + q * 4]      = p0;
    *(uint2*)&grT[(c0 + 16 + lm) * 384 + m0 + q * 4] = p1;
  }
  // layer-0 only: adjacency bitmasks (self-loop OR'd in), by==0 blocks
  if (adj != nullptr && blockIdx.y == 0) {
    int rbase = (blockIdx.x * 4 + wave) * 4;
    for (int rr = 0; rr < 4; ++rr) {
      int row = rbase + rr;
#pragma unroll
      for (int w = 0; w < 6; ++w) {
        int j = w * 64 + lane;
        u64 m = __ballot(adj[row * N_NODES + j] != 0 || row == j);
        if (lane == 0) mbits[row * 6 + w] = m;
      }
    }
  }
}

// ---------------------------------------------------------------------------
// Kernel 2/4: fused GATv2 attention (R10 + 3-barrier restructure).
// Block = (12-row i-tile, head), 384 thr, grid (32,8) = 256 blocks = 1/CU.
// Changes vs R10: (1) s_e/s_pb no longer alias s_gl -> one barrier removed;
// (2) phase-3 B-fragments (12 x short8) + epilogue resid prefetched into
// registers at kernel start, so nothing after the last barrier touches
// global; (3) s_pb pad-row zeroing moved into the DMA-overlap window.
// LDS ~80.6 KB -> still 1 block/CU.
// ---------------------------------------------------------------------------
template <int LAYER>
__global__ __launch_bounds__(384) void attn_fused(
    const float* __restrict__ G, const ushort_t* __restrict__ glb,
    const ushort_t* __restrict__ grT, const u64* __restrict__ mbits,
    const float* __restrict__ resid_in, const float* __restrict__ avec,
    float* __restrict__ xcur_out, float* __restrict__ f_out)
{
  __shared__ __align__(16) char smem[49152];          // s_gl (DMA dst only)
  __shared__ float    s_e[IT][N_NODES];               // 18432 B (separate!)
  __shared__ ushort_t s_pb[16][392];                  // 12544 B
  __shared__ float s_bri[IT];
  __shared__ u64   s_mask[IT][6];
  ushort_t (*s_gl)[64] = (ushort_t(*)[64])smem;

  const int t = threadIdx.x;
  const int i0 = blockIdx.x * IT, h = blockIdx.y;
  const int lane = t & 63, wave = t >> 6;
  const int lm = lane & 15, q = lane >> 4;

  // -- issue async global->LDS DMA first (8 x 16 B per thread) --
#pragma unroll
  for (int rep = 0; rep < 8; ++rep) {
    int idx = rep * 384 + t, row = idx >> 3, cl = idx & 7;
    int cg = cl ^ (row & 7);
    const ushort_t* gsrc = glb + row * HF + h * 64 + cg * 8;
    __builtin_amdgcn_global_load_lds(
        (const __attribute__((address_space(1))) uint32_t*)gsrc,
        (__attribute__((address_space(3))) uint32_t*)(smem + idx * 16),
        16, 0, 0);
  }

  // -- prefetch phase-3 B-fragments + epilogue resid (independent loads) --
  short8 bfrag[12];
  float  rres[4];
  if (wave < 4) {
    const ushort_t* Brow = grT + (h * 64 + wave * 16 + lm) * 384;
#pragma unroll
    for (int kc = 0; kc < 12; ++kc)
      bfrag[kc] = *(const short8*)&Brow[kc * 32 + q * 8];
    if (q < 3) {
#pragma unroll
      for (int r = 0; r < 4; ++r)
        rres[r] = resid_in[(i0 + q * 4 + r) * HF + h * 64 + wave * 16 + lm];
    }
  }

  // -- overlapped with DMA: masks (72 u64) + bri dot + s_pb pad zeroing --
  if (t < 72) ((u64*)s_mask)[t] = mbits[i0 * 6 + t];
  if (t >= 128 && t < 320) {
    int u = t - 128, il = u >> 4, fg = u & 15;
    float4 g4 = *(const float4*)(G + (i0 + il) * 1024 + 512 + h * 64 + fg * 4);
    float4 a4 = *(const float4*)(avec + fg * 4);
    float s = a4.x * g4.x + a4.y * g4.y + a4.z * g4.z + a4.w * g4.w;
    s += __shfl_xor(s, 1); s += __shfl_xor(s, 2);
    s += __shfl_xor(s, 4); s += __shfl_xor(s, 8);
    if (fg == 0) s_bri[il] = s;
  }
#pragma unroll
  for (int r4 = 0; r4 < 4; ++r4) s_pb[IT + r4][t] = 0;  // zero P rows 12..15
  __syncthreads();   // barrier 1: drains DMA + overlap work

  // -- own j-row -> 64 VGPRs (chunk cg at slot cg^(t&7)); avec -> VGPRs --
  float gl[64], av[64];
  {
    const int sw = t & 7;
#pragma unroll
    for (int cg = 0; cg < 8; ++cg) {
      short8 v = *(const short8*)&s_gl[t][(cg ^ sw) * 8];
#pragma unroll
      for (int u2 = 0; u2 < 8; ++u2)
        gl[cg * 8 + u2] = bf2f_u((ushort_t)v[u2]);
    }
#pragma unroll
    for (int c = 0; c < 16; ++c) {
      float4 a4 = ((const float4*)avec)[c];
      av[c * 4] = a4.x; av[c * 4 + 1] = a4.y;
      av[c * 4 + 2] = a4.z; av[c * 4 + 3] = a4.w;
    }
  }
  float accl = 0.f;
#pragma unroll
  for (int f = 0; f < 64; ++f) accl += av[f] * gl[f];
  // no barrier: s_e is a separate region; each thread writes its own column

  // -- phase 1: scores, written straight to LDS --
  const int jw = t >> 6, jb = t & 63;
#pragma unroll
  for (int il = 0; il < IT; ++il) {
    const float4* gr4 = (const float4*)(G + (i0 + il) * 1024 + 512 + h * 64);
    float acc = 0.f;
#pragma unroll
    for (int c = 0; c < 16; ++c) {
      float4 g4 = gr4[c];
      acc += av[c * 4]     * fabsf(gl[c * 4]     + g4.x);
      acc += av[c * 4 + 1] * fabsf(gl[c * 4 + 1] + g4.y);
      acc += av[c * 4 + 2] * fabsf(gl[c * 4 + 2] + g4.z);
      acc += av[c * 4 + 3] * fabsf(gl[c * 4 + 3] + g4.w);
    }
    bool m = (s_mask[il][jw] >> jb) & 1;
    float e = 0.6f * (accl + s_bri[il]) + 0.4f * acc;
    s_e[il][t] = m ? e : -1e30f;
  }
  __syncthreads();   // barrier 2: scores visible to softmax waves

  // -- phase 2: softmax over j per row; write normalized P bf16 --
#pragma unroll
  for (int rep = 0; rep < 2; ++rep) {
    int il = wave * 2 + rep;
    float v[6];
    float mx = -1e30f;
#pragma unroll
    for (int c = 0; c < 6; ++c) { v[c] = s_e[il][lane + 64 * c]; mx = fmaxf(mx, v[c]); }
#pragma unroll
    for (int off = 32; off; off >>= 1) mx = fmaxf(mx, __shfl_xor(mx, off));
    float sum = 0.f;
#pragma unroll
    for (int c = 0; c < 6; ++c) { v[c] = __expf(v[c] - mx); sum += v[c]; }
#pragma unroll
    for (int off = 32; off; off >>= 1) sum += __shfl_xor(sum, off);
    float inv = 1.0f / sum;
#pragma unroll
    for (int c = 0; c < 6; ++c) s_pb[il][lane + 64 * c] = f2bf(v[c] * inv);
  }
  __syncthreads();   // barrier 3: P visible to MFMA waves

  // -- phase 3: MFMA (A from LDS, B + resid already in registers) --
  if (wave < 4) {
    f32x4 acc = {0.f, 0.f, 0.f, 0.f};
#pragma unroll
    for (int kc = 0; kc < 12; ++kc) {
      short8 af = *(const short8*)&s_pb[lm][kc * 32 + q * 8];
      acc = __builtin_amdgcn_mfma_f32_16x16x32_bf16(af, bfrag[kc], acc, 0, 0, 0);
    }
    if (q < 3) {                                    // D rows 0..11
#pragma unroll
      for (int r = 0; r < 4; ++r) {
        int i = i0 + q * 4 + r;
        int off = i * HF + h * 64 + wave * 16 + lm;
        float o = acc[r];
        if (LAYER == 0) {
          float oe = (o > 0.f) ? o : (__expf(o) - 1.f);   // ELU
          xcur_out[off] = rres[r] + oe;   // fp32 residual for layer 1
        } else {
          f_out[off] = rres[r] + o;       // final output, fp32
        }
      }
    }
  }
}

// ---------------------------------------------------------------------------
extern "C" void kernel_launch(void* const* d_in, const int* in_sizes, int n_in,
                              void* d_out, int out_size, void* d_ws, size_t ws_size,
                              hipStream_t stream) {
  const float* x   = (const float*)d_in[0];
  const int*   adj = (const int*)d_in[1];
  const float* Wl0 = (const float*)d_in[2];
  const float* Wr0 = (const float*)d_in[3];
  const float* a0  = (const float*)d_in[4];
  const float* Wl1 = (const float*)d_in[5];
  const float* Wr1 = (const float*)d_in[6];
  const float* a1  = (const float*)d_in[7];
  float* out = (float*)d_out;

  char* ws = (char*)d_ws;
  float*    G    = (float*)   (ws + 0L);            // 1.5 MB (gr half used)
  ushort_t* grT  = (ushort_t*)(ws + (2L << 20));    // 384 KB gr^T bf16
  ushort_t* glb  = (ushort_t*)(ws + (3L << 20));    // 384 KB gl bf16
  u64*      mbits= (u64*)     (ws + (4L << 20));    // 18 KB adjacency bits
  float*    xcur = (float*)   (ws + (5L << 20));    // 768 KB fp32 residual

  gemm_direct<<<dim3(24, 8), 256, 0, stream>>>(x, Wl0, Wr0, G, glb, grT,
                                               adj, mbits);
  attn_fused<0><<<dim3(32, 8), 384, 0, stream>>>(G, glb, grT, mbits, x, a0,
                                                 xcur, nullptr);
  gemm_direct<<<dim3(24, 8), 256, 0, stream>>>(xcur, Wl1, Wr1, G, glb, grT,
                                               nullptr, nullptr);
  attn_fused<1><<<dim3(32, 8), 384, 0, stream>>>(G, glb, grT, mbits, xcur, a1,
                                                 nullptr, out);
}